// Round 6
// baseline (208.599 us; speedup 1.0000x reference)
//
#include <hip/hip_runtime.h>
#include <hip/hip_bf16.h>
#include <math.h>

#define NROW 4096
#define DIM  1024

typedef short v8s __attribute__((ext_vector_type(8)));
typedef float v4f __attribute__((ext_vector_type(4)));

__device__ __forceinline__ ushort f2bf(float f) {
    __hip_bfloat16 h = __float2bfloat16(f);
    union { __hip_bfloat16 h; ushort u; } x; x.h = h; return x.u;
}

// ---------------------------------------------------------------- row stats (fp32 inputs)
// Per-row: s_i, s_j (fp64 dots -- branch-critical for sigmoid>0.8), zero_norm,
// and the attract/repulse row coefficients.
__global__ __launch_bounds__(256) void k_rowstats(
    const float* __restrict__ vecs, const float* __restrict__ mass,
    const float* __restrict__ hops, const int* __restrict__ alive,
    const int* __restrict__ is_photon, const float* __restrict__ wci,
    const float* __restrict__ wcj, const float* __restrict__ logc,
    const float* __restrict__ logG,
    double* __restrict__ s_i, double* __restrict__ s_j,
    float* __restrict__ rowAtt, float* __restrict__ rowRep,
    float* __restrict__ massF, int* __restrict__ flags)
{
    const int row = blockIdx.x, t = threadIdx.x;
    const float* vr = vecs + (size_t)row * DIM;
    const int base = t * 4;
    float4 pv = *(const float4*)&vr[base];
    float4 pi = *(const float4*)&wci[base];
    float4 pj = *(const float4*)&wcj[base];
    double di = (double)pv.x * pi.x + (double)pv.y * pi.y + (double)pv.z * pi.z + (double)pv.w * pi.w;
    double dj = (double)pv.x * pj.x + (double)pv.y * pj.y + (double)pv.z * pj.z + (double)pv.w * pj.w;
    double ss = (double)pv.x * pv.x + (double)pv.y * pv.y + (double)pv.z * pv.z + (double)pv.w * pv.w;
    #pragma unroll
    for (int off = 32; off > 0; off >>= 1) {
        di += __shfl_down(di, off);
        dj += __shfl_down(dj, off);
        ss += __shfl_down(ss, off);
    }
    __shared__ double rd[3][4];
    const int wid = t >> 6;
    if ((t & 63) == 0) { rd[0][wid] = di; rd[1][wid] = dj; rd[2][wid] = ss; }
    __syncthreads();
    if (t == 0) {
        di = rd[0][0] + rd[0][1] + rd[0][2] + rd[0][3];
        dj = rd[1][0] + rd[1][1] + rd[1][2] + rd[1][3];
        ss = rd[2][0] + rd[2][1] + rd[2][2] + rd[2][3];
        double c  = fmax(exp((double)logc[0]), 1e-6);
        double G  = exp((double)logG[0]);
        double dl = (double)hops[row] / c;
        double lam = (is_photon[row] != 0) ? 1.0 : exp(-dl);
        double rs  = fmax(dl, 0.1);
        double cd  = (dl <= 1.0) ? 1.0 : exp(-dl + 1.0);
        double m   = (double)mass[row];
        s_i[row] = di;
        s_j[row] = dj;
        rowAtt[row] = (float)(lam * G * m / (rs * rs) * cd);  // * m_j * (0.5+0.5R)
        rowRep[row] = (float)(-lam * m);                      // * conflict * m_j
        massF[row]  = (float)m;
        flags[row]  = ((alive[row] != 0) ? 1 : 0) | ((sqrt(ss) < 1e-8) ? 2 : 0);
    }
}

// ---------------------------------------------------------------- v = vecs @ W^T + b
// fp32 inputs converted to bf16 during LDS staging; 128x128 tile, BK=32,
// 4 waves 2x2, mfma 16x16x32 bf16; bf16 result to vn workspace.
__global__ __launch_bounds__(256) void k_proj(
    const float* __restrict__ A, const float* __restrict__ B,
    const float* __restrict__ bias, ushort* __restrict__ vout)
{
    __shared__ ushort As[128 * 32], Bs[128 * 32];
    const int t = threadIdx.x;
    const int m0 = blockIdx.y * 128, n0 = blockIdx.x * 128;
    const int wid = t >> 6, lane = t & 63;
    const int wm = wid >> 1, wn = wid & 1;
    const int quad = lane >> 4, l16 = lane & 15;
    v4f acc[4][4];
    #pragma unroll
    for (int i = 0; i < 4; i++)
        #pragma unroll
        for (int j = 0; j < 4; j++) acc[i][j] = (v4f){0.f, 0.f, 0.f, 0.f};

    for (int k0 = 0; k0 < DIM; k0 += 32) {
        #pragma unroll
        for (int p = 0; p < 4; ++p) {
            int c = p * 256 + t;               // 128 rows x 8 float4-chunks
            int r = c >> 3, co = (c & 7) * 4;
            float4 fa = *(const float4*)&A[(size_t)(m0 + r) * DIM + k0 + co];
            float4 fb = *(const float4*)&B[(size_t)(n0 + r) * DIM + k0 + co];
            ushort4 ua, ub;
            ua.x = f2bf(fa.x); ua.y = f2bf(fa.y); ua.z = f2bf(fa.z); ua.w = f2bf(fa.w);
            ub.x = f2bf(fb.x); ub.y = f2bf(fb.y); ub.z = f2bf(fb.z); ub.w = f2bf(fb.w);
            *(ushort4*)&As[r * 32 + co] = ua;
            *(ushort4*)&Bs[r * 32 + co] = ub;
        }
        __syncthreads();
        v8s af[4], bfr[4];
        #pragma unroll
        for (int mi = 0; mi < 4; mi++) af[mi]  = *(const v8s*)&As[(wm * 64 + mi * 16 + l16) * 32 + quad * 8];
        #pragma unroll
        for (int ni = 0; ni < 4; ni++) bfr[ni] = *(const v8s*)&Bs[(wn * 64 + ni * 16 + l16) * 32 + quad * 8];
        #pragma unroll
        for (int mi = 0; mi < 4; mi++)
            #pragma unroll
            for (int ni = 0; ni < 4; ni++)
                acc[mi][ni] = __builtin_amdgcn_mfma_f32_16x16x32_bf16(af[mi], bfr[ni], acc[mi][ni], 0, 0, 0);
        __syncthreads();
    }
    float bcol[4];
    #pragma unroll
    for (int ni = 0; ni < 4; ni++) bcol[ni] = bias[n0 + wn * 64 + ni * 16 + l16];
    #pragma unroll
    for (int mi = 0; mi < 4; mi++)
        #pragma unroll
        for (int r = 0; r < 4; r++) {
            int row = m0 + wm * 64 + mi * 16 + quad * 4 + r;
            #pragma unroll
            for (int ni = 0; ni < 4; ni++) {
                int col = n0 + wn * 64 + ni * 16 + l16;
                vout[(size_t)row * DIM + col] = f2bf(acc[mi][ni][r] + bcol[ni]);
            }
        }
}

// ---------------------------------------------------------------- row-normalize v (bf16, in place)
__global__ __launch_bounds__(256) void k_norm(ushort* __restrict__ v)
{
    const int row = blockIdx.x, t = threadIdx.x;
    ushort* vr = v + (size_t)row * DIM;
    ushort4 pv = *(const ushort4*)&vr[t * 4];
    union { unsigned i; float f; } c0, c1, c2, c3;
    c0.i = ((unsigned)pv.x) << 16; c1.i = ((unsigned)pv.y) << 16;
    c2.i = ((unsigned)pv.z) << 16; c3.i = ((unsigned)pv.w) << 16;
    float x0 = c0.f, x1 = c1.f, x2 = c2.f, x3 = c3.f;
    float ss = x0 * x0 + x1 * x1 + x2 * x2 + x3 * x3;
    #pragma unroll
    for (int off = 32; off > 0; off >>= 1) ss += __shfl_down(ss, off);
    __shared__ float r4[4];
    __shared__ float sinv;
    if ((t & 63) == 0) r4[t >> 6] = ss;
    __syncthreads();
    if (t == 0) sinv = 1.0f / fmaxf(sqrtf(r4[0] + r4[1] + r4[2] + r4[3]), 1e-8f);
    __syncthreads();
    float inv = sinv;
    ushort4 o;
    o.x = f2bf(x0 * inv); o.y = f2bf(x1 * inv); o.z = f2bf(x2 * inv); o.w = f2bf(x3 * inv);
    *(ushort4*)&vr[t * 4] = o;
}

// ---------------------------------------------------------------- phi tiles -> FP32 output
// Tile (bi,bj) of 128x128. bi>=bj needs R (GEMM over vn); bi<bj is epilogue-only
// (attract is zero above the diagonal, repulse doesn't use R).
__global__ __launch_bounds__(256) void k_phi(
    const ushort* __restrict__ vn,
    const double* __restrict__ s_i, const double* __restrict__ s_j,
    const float* __restrict__ rowAtt, const float* __restrict__ rowRep,
    const float* __restrict__ massF, const int* __restrict__ flags,
    const float* __restrict__ bconf_p, float* __restrict__ out)
{
    __shared__ ushort As[128 * 32], Bs[128 * 32];
    const int t = threadIdx.x;
    const int bi = blockIdx.y, bj = blockIdx.x;
    const int m0 = bi * 128, n0 = bj * 128;
    const int wid = t >> 6, lane = t & 63;
    const int wm = wid >> 1, wn = wid & 1;
    const int quad = lane >> 4, l16 = lane & 15;
    v4f acc[4][4];
    #pragma unroll
    for (int i = 0; i < 4; i++)
        #pragma unroll
        for (int j = 0; j < 4; j++) acc[i][j] = (v4f){0.f, 0.f, 0.f, 0.f};

    if (bi >= bj) {
        for (int k0 = 0; k0 < DIM; k0 += 32) {
            #pragma unroll
            for (int p = 0; p < 2; ++p) {
                int c = p * 256 + t;
                int r = c >> 2, co = (c & 3) * 8;
                *(uint4*)&As[r * 32 + co] = *(const uint4*)&vn[(size_t)(m0 + r) * DIM + k0 + co];
                *(uint4*)&Bs[r * 32 + co] = *(const uint4*)&vn[(size_t)(n0 + r) * DIM + k0 + co];
            }
            __syncthreads();
            v8s af[4], bfr[4];
            #pragma unroll
            for (int mi = 0; mi < 4; mi++) af[mi]  = *(const v8s*)&As[(wm * 64 + mi * 16 + l16) * 32 + quad * 8];
            #pragma unroll
            for (int ni = 0; ni < 4; ni++) bfr[ni] = *(const v8s*)&Bs[(wn * 64 + ni * 16 + l16) * 32 + quad * 8];
            #pragma unroll
            for (int mi = 0; mi < 4; mi++)
                #pragma unroll
                for (int ni = 0; ni < 4; ni++)
                    acc[mi][ni] = __builtin_amdgcn_mfma_f32_16x16x32_bf16(af[mi], bfr[ni], acc[mi][ni], 0, 0, 0);
            __syncthreads();
        }
    }

    const double bc  = (double)bconf_p[0];
    const double LN4 = 1.3862943611198906;  // sigmoid(x)>0.8  <=>  x>ln4
    float  cm[4]; double csj[4]; int cf[4]; int ccol[4];
    #pragma unroll
    for (int ni = 0; ni < 4; ni++) {
        int col = n0 + wn * 64 + ni * 16 + l16;
        ccol[ni] = col; cm[ni] = massF[col]; csj[ni] = s_j[col]; cf[ni] = flags[col];
    }
    #pragma unroll
    for (int mi = 0; mi < 4; mi++)
        #pragma unroll
        for (int r = 0; r < 4; r++) {
            int row = m0 + wm * 64 + mi * 16 + quad * 4 + r;
            float  rA = rowAtt[row], rR = rowRep[row];
            int    fi = flags[row];
            double si = s_i[row];
            size_t ob = (size_t)row * NROW;
            #pragma unroll
            for (int ni = 0; ni < 4; ni++) {
                int col = ccol[ni];
                double x = si + csj[ni] + bc;
                float conflict = 1.0f / (1.0f + expf(-(float)x));
                bool  chigh = x > LN4;
                bool  gate  = ((fi & cf[ni]) & 1) && (row != col);
                float Rv  = ((fi | cf[ni]) & 2) ? 0.0f : acc[mi][ni][r];
                float att = (col < row) ? rA * cm[ni] * (0.5f + 0.5f * Rv) : 0.0f;
                float ph  = gate ? (chigh ? rR * conflict * cm[ni] : att) : 0.0f;
                out[ob + col] = ph;   // FP32 output
            }
        }
}

extern "C" void kernel_launch(void* const* d_in, const int* in_sizes, int n_in,
                              void* d_out, int out_size, void* d_ws, size_t ws_size,
                              hipStream_t stream)
{
    const float* vecs      = (const float*)d_in[0];
    const float* mass      = (const float*)d_in[1];
    const float* hops      = (const float*)d_in[2];
    const int*   alive     = (const int*)d_in[3];
    const int*   is_photon = (const int*)d_in[4];
    const float* W         = (const float*)d_in[5];
    const float* Wb        = (const float*)d_in[6];
    const float* wci       = (const float*)d_in[7];
    const float* wcj       = (const float*)d_in[8];
    const float* bconf     = (const float*)d_in[9];
    const float* logc      = (const float*)d_in[10];
    const float* logG      = (const float*)d_in[11];

    char* ws = (char*)d_ws;
    double* s_i    = (double*)(ws);                  // 32 KB
    double* s_j    = (double*)(ws + 32768);          // 32 KB
    float*  rowAtt = (float*)(ws + 65536);           // 16 KB
    float*  rowRep = (float*)(ws + 81920);           // 16 KB
    float*  massF  = (float*)(ws + 98304);           // 16 KB
    int*    flagsA = (int*)(ws + 114688);            // 16 KB
    ushort* vn     = (ushort*)(ws + 131072);         // 8 MB  (total ~8.5 MB, ws >= 10 MB verified r4)

    k_rowstats<<<dim3(NROW), dim3(256), 0, stream>>>(
        vecs, mass, hops, alive, is_photon, wci, wcj, logc, logG,
        s_i, s_j, rowAtt, rowRep, massF, flagsA);
    k_proj<<<dim3(DIM / 128, NROW / 128), dim3(256), 0, stream>>>(vecs, W, Wb, vn);
    k_norm<<<dim3(NROW), dim3(256), 0, stream>>>(vn);
    k_phi<<<dim3(NROW / 128, NROW / 128), dim3(256), 0, stream>>>(
        vn, s_i, s_j, rowAtt, rowRep, massF, flagsA, bconf, (float*)d_out);
}

// Round 7
// 204.537 us; speedup vs baseline: 1.0199x; 1.0199x over previous
//
#include <hip/hip_runtime.h>
#include <hip/hip_bf16.h>
#include <math.h>

#define NROW 4096
#define DIM  1024

typedef short v8s __attribute__((ext_vector_type(8)));
typedef float v4f __attribute__((ext_vector_type(4)));

__device__ __forceinline__ ushort f2bf(float f) {
    __hip_bfloat16 h = __float2bfloat16(f);
    union { __hip_bfloat16 h; ushort u; } x; x.h = h; return x.u;
}

// ---------------------------------------------------------------- row stats (fp32 inputs)
__global__ __launch_bounds__(256) void k_rowstats(
    const float* __restrict__ vecs, const float* __restrict__ mass,
    const float* __restrict__ hops, const int* __restrict__ alive,
    const int* __restrict__ is_photon, const float* __restrict__ wci,
    const float* __restrict__ wcj, const float* __restrict__ logc,
    const float* __restrict__ logG,
    double* __restrict__ s_i, double* __restrict__ s_j,
    float* __restrict__ rowAtt, float* __restrict__ rowRep,
    float* __restrict__ massF, int* __restrict__ flags)
{
    const int row = blockIdx.x, t = threadIdx.x;
    const float* vr = vecs + (size_t)row * DIM;
    const int base = t * 4;
    float4 pv = *(const float4*)&vr[base];
    float4 pi = *(const float4*)&wci[base];
    float4 pj = *(const float4*)&wcj[base];
    double di = (double)pv.x * pi.x + (double)pv.y * pi.y + (double)pv.z * pi.z + (double)pv.w * pi.w;
    double dj = (double)pv.x * pj.x + (double)pv.y * pj.y + (double)pv.z * pj.z + (double)pv.w * pj.w;
    double ss = (double)pv.x * pv.x + (double)pv.y * pv.y + (double)pv.z * pv.z + (double)pv.w * pv.w;
    #pragma unroll
    for (int off = 32; off > 0; off >>= 1) {
        di += __shfl_down(di, off);
        dj += __shfl_down(dj, off);
        ss += __shfl_down(ss, off);
    }
    __shared__ double rd[3][4];
    const int wid = t >> 6;
    if ((t & 63) == 0) { rd[0][wid] = di; rd[1][wid] = dj; rd[2][wid] = ss; }
    __syncthreads();
    if (t == 0) {
        di = rd[0][0] + rd[0][1] + rd[0][2] + rd[0][3];
        dj = rd[1][0] + rd[1][1] + rd[1][2] + rd[1][3];
        ss = rd[2][0] + rd[2][1] + rd[2][2] + rd[2][3];
        double c  = fmax(exp((double)logc[0]), 1e-6);
        double G  = exp((double)logG[0]);
        double dl = (double)hops[row] / c;
        double lam = (is_photon[row] != 0) ? 1.0 : exp(-dl);
        double rs  = fmax(dl, 0.1);
        double cd  = (dl <= 1.0) ? 1.0 : exp(-dl + 1.0);
        double m   = (double)mass[row];
        s_i[row] = di;
        s_j[row] = dj;
        rowAtt[row] = (float)(lam * G * m / (rs * rs) * cd);  // * m_j * (0.5+0.5R)
        rowRep[row] = (float)(-lam * m);                      // * conflict * m_j
        massF[row]  = (float)m;
        flags[row]  = ((alive[row] != 0) ? 1 : 0) | ((sqrt(ss) < 1e-8) ? 2 : 0);
    }
}

// ---------------------------------------------------------------- v = vecs @ W^T + b
__global__ __launch_bounds__(256) void k_proj(
    const float* __restrict__ A, const float* __restrict__ B,
    const float* __restrict__ bias, ushort* __restrict__ vout)
{
    __shared__ ushort As[128 * 32], Bs[128 * 32];
    const int t = threadIdx.x;
    const int m0 = blockIdx.y * 128, n0 = blockIdx.x * 128;
    const int wid = t >> 6, lane = t & 63;
    const int wm = wid >> 1, wn = wid & 1;
    const int quad = lane >> 4, l16 = lane & 15;
    v4f acc[4][4];
    #pragma unroll
    for (int i = 0; i < 4; i++)
        #pragma unroll
        for (int j = 0; j < 4; j++) acc[i][j] = (v4f){0.f, 0.f, 0.f, 0.f};

    for (int k0 = 0; k0 < DIM; k0 += 32) {
        #pragma unroll
        for (int p = 0; p < 4; ++p) {
            int c = p * 256 + t;               // 128 rows x 8 float4-chunks
            int r = c >> 3, co = (c & 7) * 4;
            float4 fa = *(const float4*)&A[(size_t)(m0 + r) * DIM + k0 + co];
            float4 fb = *(const float4*)&B[(size_t)(n0 + r) * DIM + k0 + co];
            ushort4 ua, ub;
            ua.x = f2bf(fa.x); ua.y = f2bf(fa.y); ua.z = f2bf(fa.z); ua.w = f2bf(fa.w);
            ub.x = f2bf(fb.x); ub.y = f2bf(fb.y); ub.z = f2bf(fb.z); ub.w = f2bf(fb.w);
            *(ushort4*)&As[r * 32 + co] = ua;
            *(ushort4*)&Bs[r * 32 + co] = ub;
        }
        __syncthreads();
        v8s af[4], bfr[4];
        #pragma unroll
        for (int mi = 0; mi < 4; mi++) af[mi]  = *(const v8s*)&As[(wm * 64 + mi * 16 + l16) * 32 + quad * 8];
        #pragma unroll
        for (int ni = 0; ni < 4; ni++) bfr[ni] = *(const v8s*)&Bs[(wn * 64 + ni * 16 + l16) * 32 + quad * 8];
        #pragma unroll
        for (int mi = 0; mi < 4; mi++)
            #pragma unroll
            for (int ni = 0; ni < 4; ni++)
                acc[mi][ni] = __builtin_amdgcn_mfma_f32_16x16x32_bf16(af[mi], bfr[ni], acc[mi][ni], 0, 0, 0);
        __syncthreads();
    }
    float bcol[4];
    #pragma unroll
    for (int ni = 0; ni < 4; ni++) bcol[ni] = bias[n0 + wn * 64 + ni * 16 + l16];
    #pragma unroll
    for (int mi = 0; mi < 4; mi++)
        #pragma unroll
        for (int r = 0; r < 4; r++) {
            int row = m0 + wm * 64 + mi * 16 + quad * 4 + r;
            #pragma unroll
            for (int ni = 0; ni < 4; ni++) {
                int col = n0 + wn * 64 + ni * 16 + l16;
                vout[(size_t)row * DIM + col] = f2bf(acc[mi][ni][r] + bcol[ni]);
            }
        }
}

// ---------------------------------------------------------------- row-normalize v (bf16, in place)
__global__ __launch_bounds__(256) void k_norm(ushort* __restrict__ v)
{
    const int row = blockIdx.x, t = threadIdx.x;
    ushort* vr = v + (size_t)row * DIM;
    ushort4 pv = *(const ushort4*)&vr[t * 4];
    union { unsigned i; float f; } c0, c1, c2, c3;
    c0.i = ((unsigned)pv.x) << 16; c1.i = ((unsigned)pv.y) << 16;
    c2.i = ((unsigned)pv.z) << 16; c3.i = ((unsigned)pv.w) << 16;
    float x0 = c0.f, x1 = c1.f, x2 = c2.f, x3 = c3.f;
    float ss = x0 * x0 + x1 * x1 + x2 * x2 + x3 * x3;
    #pragma unroll
    for (int off = 32; off > 0; off >>= 1) ss += __shfl_down(ss, off);
    __shared__ float r4[4];
    __shared__ float sinv;
    if ((t & 63) == 0) r4[t >> 6] = ss;
    __syncthreads();
    if (t == 0) sinv = 1.0f / fmaxf(sqrtf(r4[0] + r4[1] + r4[2] + r4[3]), 1e-8f);
    __syncthreads();
    float inv = sinv;
    ushort4 o;
    o.x = f2bf(x0 * inv); o.y = f2bf(x1 * inv); o.z = f2bf(x2 * inv); o.w = f2bf(x3 * inv);
    *(ushort4*)&vr[t * 4] = o;
}

// ---------------------------------------------------------------- phi tiles -> FP32 output
// 1D grid of 1024 blocks; Bresenham-interleaved heavy (bi>=bj, GEMM) and
// light (bi<bj, epilogue-only) tiles for even CU load. Heavy staging uses
// global_load_lds width=16 (wave-uniform LDS base + lane*16 contract).
__global__ __launch_bounds__(256) void k_phi(
    const ushort* __restrict__ vn,
    const double* __restrict__ s_i, const double* __restrict__ s_j,
    const float* __restrict__ rowAtt, const float* __restrict__ rowRep,
    const float* __restrict__ massF, const int* __restrict__ flags,
    const float* __restrict__ bconf_p, float* __restrict__ out)
{
    __shared__ ushort As[128 * 32], Bs[128 * 32];
    const int t = threadIdx.x;
    const int id = blockIdx.x;

    // heavies before id = (id*528)>>10 ; id is heavy iff count increments at id
    const int h  = (id * 528) >> 10;
    const int h2 = ((id + 1) * 528) >> 10;
    const bool heavy = (h2 > h);
    int bi, bj;
    if (heavy) {
        int r = 0;                       // decode h = r*(r+1)/2 + bj, bj<=r
        while (h >= ((r + 1) * (r + 2)) >> 1) ++r;
        bi = r; bj = h - ((r * (r + 1)) >> 1);
    } else {
        int l = id - h;                  // light index in [0,496)
        int r = 0;
        while (l >= 31 - r) { l -= 31 - r; ++r; }
        bi = r; bj = r + 1 + l;
    }
    const int m0 = bi * 128, n0 = bj * 128;
    const int wid = t >> 6, lane = t & 63;
    const int wm = wid >> 1, wn = wid & 1;
    const int quad = lane >> 4, l16 = lane & 15;
    v4f acc[4][4];
    #pragma unroll
    for (int i = 0; i < 4; i++)
        #pragma unroll
        for (int j = 0; j < 4; j++) acc[i][j] = (v4f){0.f, 0.f, 0.f, 0.f};

    if (heavy) {
        for (int k0 = 0; k0 < DIM; k0 += 32) {
            // async global->LDS staging: wave w pass p stages chunks (2w+p)*64+lane
            // (chunk c: row=c>>2, col8=c&3 of the row-major 128x32 bf16 tile)
            #pragma unroll
            for (int p = 0; p < 2; ++p) {
                int c = (wid * 2 + p) * 64 + lane;
                int r = c >> 2, co = (c & 3) * 8;
                const ushort* ga = &vn[(size_t)(m0 + r) * DIM + k0 + co];
                const ushort* gb = &vn[(size_t)(n0 + r) * DIM + k0 + co];
                __builtin_amdgcn_global_load_lds(
                    (const __attribute__((address_space(1))) void*)ga,
                    (__attribute__((address_space(3))) void*)&As[(wid * 2 + p) * 512], 16, 0, 0);
                __builtin_amdgcn_global_load_lds(
                    (const __attribute__((address_space(1))) void*)gb,
                    (__attribute__((address_space(3))) void*)&Bs[(wid * 2 + p) * 512], 16, 0, 0);
            }
            __syncthreads();
            v8s af[4], bfr[4];
            #pragma unroll
            for (int mi = 0; mi < 4; mi++) af[mi]  = *(const v8s*)&As[(wm * 64 + mi * 16 + l16) * 32 + quad * 8];
            #pragma unroll
            for (int ni = 0; ni < 4; ni++) bfr[ni] = *(const v8s*)&Bs[(wn * 64 + ni * 16 + l16) * 32 + quad * 8];
            #pragma unroll
            for (int mi = 0; mi < 4; mi++)
                #pragma unroll
                for (int ni = 0; ni < 4; ni++)
                    acc[mi][ni] = __builtin_amdgcn_mfma_f32_16x16x32_bf16(af[mi], bfr[ni], acc[mi][ni], 0, 0, 0);
            __syncthreads();
        }
    }

    const double bc  = (double)bconf_p[0];
    const double LN4 = 1.3862943611198906;  // sigmoid(x)>0.8  <=>  x>ln4
    float  cm[4]; double csj[4]; int cf[4]; int ccol[4];
    #pragma unroll
    for (int ni = 0; ni < 4; ni++) {
        int col = n0 + wn * 64 + ni * 16 + l16;
        ccol[ni] = col; cm[ni] = massF[col]; csj[ni] = s_j[col]; cf[ni] = flags[col];
    }
    #pragma unroll
    for (int mi = 0; mi < 4; mi++)
        #pragma unroll
        for (int r = 0; r < 4; r++) {
            int row = m0 + wm * 64 + mi * 16 + quad * 4 + r;
            float  rA = rowAtt[row], rR = rowRep[row];
            int    fi = flags[row];
            double si = s_i[row];
            size_t ob = (size_t)row * NROW;
            #pragma unroll
            for (int ni = 0; ni < 4; ni++) {
                int col = ccol[ni];
                double x = si + csj[ni] + bc;
                float conflict = 1.0f / (1.0f + expf(-(float)x));
                bool  chigh = x > LN4;
                bool  gate  = ((fi & cf[ni]) & 1) && (row != col);
                float Rv  = ((fi | cf[ni]) & 2) ? 0.0f : acc[mi][ni][r];
                float att = (col < row) ? rA * cm[ni] * (0.5f + 0.5f * Rv) : 0.0f;
                float ph  = gate ? (chigh ? rR * conflict * cm[ni] : att) : 0.0f;
                out[ob + col] = ph;   // FP32 output
            }
        }
}

extern "C" void kernel_launch(void* const* d_in, const int* in_sizes, int n_in,
                              void* d_out, int out_size, void* d_ws, size_t ws_size,
                              hipStream_t stream)
{
    const float* vecs      = (const float*)d_in[0];
    const float* mass      = (const float*)d_in[1];
    const float* hops      = (const float*)d_in[2];
    const int*   alive     = (const int*)d_in[3];
    const int*   is_photon = (const int*)d_in[4];
    const float* W         = (const float*)d_in[5];
    const float* Wb        = (const float*)d_in[6];
    const float* wci       = (const float*)d_in[7];
    const float* wcj       = (const float*)d_in[8];
    const float* bconf     = (const float*)d_in[9];
    const float* logc      = (const float*)d_in[10];
    const float* logG      = (const float*)d_in[11];

    char* ws = (char*)d_ws;
    double* s_i    = (double*)(ws);                  // 32 KB
    double* s_j    = (double*)(ws + 32768);          // 32 KB
    float*  rowAtt = (float*)(ws + 65536);           // 16 KB
    float*  rowRep = (float*)(ws + 81920);           // 16 KB
    float*  massF  = (float*)(ws + 98304);           // 16 KB
    int*    flagsA = (int*)(ws + 114688);            // 16 KB
    ushort* vn     = (ushort*)(ws + 131072);         // 8 MB

    k_rowstats<<<dim3(NROW), dim3(256), 0, stream>>>(
        vecs, mass, hops, alive, is_photon, wci, wcj, logc, logG,
        s_i, s_j, rowAtt, rowRep, massF, flagsA);
    k_proj<<<dim3(DIM / 128, NROW / 128), dim3(256), 0, stream>>>(vecs, W, Wb, vn);
    k_norm<<<dim3(NROW), dim3(256), 0, stream>>>(vn);
    k_phi<<<dim3(1024), dim3(256), 0, stream>>>(
        vn, s_i, s_j, rowAtt, rowRep, massF, flagsA, bconf, (float*)d_out);
}